// Round 6
// baseline (315.525 us; speedup 1.0000x reference)
//
#include <hip/hip_runtime.h>

// RRSVM rank-weighted pooling, 3x3 / stride 2 / pad 1.
// x: [B=32, C=64, H=112, W=112] fp32;  s: [C, 3, 3] fp32
// out0: [B,C,56,56] fp32 ; out1: order [B,C,56,56,9] written as fp32.
//
// R6: RPT=8 / BLK=512 (full 32-wave occupancy, 6% input over-fetch,
// half the barriers) + nontemporal loads on x staging. nt stores kept
// (R5: -10us). Model: ~240us of dur is harness overhead; kernel ~74us
// vs ~58us traffic floor (360 MB @ 6.3 TB/s).

typedef float nfloat4 __attribute__((ext_vector_type(4)));

constexpr int B  = 32;
constexpr int C  = 64;
constexpr int H  = 112;
constexpr int W  = 112;
constexpr int HO = 56;
constexpr int WO = 56;
constexpr int KK = 9;
constexpr int NPIX = HO * WO;          // 3136 windows per (b,c) plane
constexpr int BLK  = 512;              // 8 waves
constexpr int LROW = 128;              // LDS row stride (floats)
constexpr int RPT  = 8;                // window-rows per block
constexpr int IR   = 2 * RPT + 1;      // input rows staged = 17

__global__ __launch_bounds__(BLK) void rrsvm_kernel(
    const float* __restrict__ x, const float* __restrict__ s,
    float* __restrict__ out, float* __restrict__ order)
{
    __shared__ float lx[IR * LROW];            // 17*128*4 = 8704 B
    __shared__ float lorder[RPT * WO * KK];    // 448*9*4 = 16128 B

    const int plane = blockIdx.y;              // b*C + c (block-uniform)
    const int ho0   = blockIdx.x;              // tile of 8 window-rows
    const int tid   = threadIdx.x;
    const int w     = tid >> 6;                // wave id 0..7 -> window-row
    const int lane  = tid & 63;                // lane -> window-col (56 live)
    const int c     = plane & (C - 1);

    const float* xp = x + (size_t)plane * (H * W);

    // ---- Stage 17 input rows (global rows 16*ho0-1 .. 16*ho0+15), shifted
    // +1 in LDS so logical col -1 lands on the zeroed entry 0.
    if (tid < IR * (W / 4)) {                  // 476 float4 tasks, one pass
        const int r  = tid / (W / 4);          // 0..16
        const int cc = tid - r * (W / 4);      // 0..27
        const int grow = 16 * ho0 - 1 + r;     // -1..111
        nfloat4 val = (nfloat4)0.0f;
        if ((unsigned)grow < (unsigned)H)      // only ho0==0, r==0 is OOB
            val = __builtin_nontemporal_load(
                      (const nfloat4*)(xp + grow * W + 4 * cc));
        float* dst = &lx[r * LROW + 1 + 4 * cc];
        dst[0] = val.x; dst[1] = val.y; dst[2] = val.z; dst[3] = val.w;
    }
    if (tid < IR) lx[tid * LROW] = 0.0f;       // logical col -1 = pad zero
    __syncthreads();

    // ---- Gather window from LDS (stride 2 -> 2-way bank alias, free).
    const bool live = (lane < WO);
    const int  lc   = live ? lane : 0;
    const int  ho   = ho0 * RPT + w;

    float v[KK];
    float fid[KK];
#pragma unroll
    for (int dy = 0; dy < 3; ++dy)
#pragma unroll
        for (int dx = 0; dx < 3; ++dx) {
            const int k = dy * 3 + dx;
            v[k]   = lx[(2 * w + dy) * LROW + 2 * lc + dx];
            fid[k] = (float)k;                 // compile-time constant
        }

    // ---- Sort descending by value; exact tie -> smaller index first.
    // Strict total order == jnp's stable argsort(-patches).
    auto CE = [&](int a, int b) {
        const float va = v[a],   vb = v[b];
        const float fa = fid[a], fb = fid[b];
        const bool sw = (va < vb) || ((va == vb) && (fa > fb));
        v[a]   = sw ? vb : va;  v[b]   = sw ? va : vb;
        fid[a] = sw ? fb : fa;  fid[b] = sw ? fa : fb;
    };
    // Batcher odd-even mergesort on 0..7 (19 CEs) + insertion of 8 (8 CEs).
    CE(0,1); CE(2,3); CE(4,5); CE(6,7);
    CE(0,2); CE(1,3); CE(4,6); CE(5,7);
    CE(1,2); CE(5,6);
    CE(0,4); CE(1,5); CE(2,6); CE(3,7);
    CE(2,4); CE(3,5);
    CE(1,2); CE(3,4); CE(5,6);
    CE(7,8); CE(6,7); CE(5,6); CE(4,5); CE(3,4); CE(2,3); CE(1,2); CE(0,1);

    // ---- Weighted sum with per-channel rank weights (block-uniform c).
    const float* sc = s + c * KK;
    float acc = 0.0f;
#pragma unroll
    for (int k = 0; k < KK; ++k) acc = fmaf(v[k], sc[k], acc);

    if (live) {
        __builtin_nontemporal_store(acc, out + (size_t)plane * NPIX + ho * WO + lane);
        const int widx = w * WO + lane;        // window within tile, 0..447
#pragma unroll
        for (int k = 0; k < KK; ++k)
            lorder[widx * KK + k] = fid[k];    // stride 9 -> 2-way, free
    }
    __syncthreads();

    // ---- Coalesced nontemporal float4 writeback of the tile's order chunk.
    // Base float idx = (plane*3136 + ho0*448)*9 : divisible by 4.
    nfloat4* __restrict__ ob =
        (nfloat4*)(order + ((size_t)plane * NPIX + (size_t)ho0 * RPT * WO) * KK);
    const nfloat4* __restrict__ lb = (const nfloat4*)lorder;
#pragma unroll
    for (int i = tid; i < RPT * WO * KK / 4; i += BLK)  // 1008 float4
        __builtin_nontemporal_store(lb[i], ob + i);
}

extern "C" void kernel_launch(void* const* d_in, const int* in_sizes, int n_in,
                              void* d_out, int out_size, void* d_ws, size_t ws_size,
                              hipStream_t stream) {
    const float* x = (const float*)d_in[0];
    const float* s = (const float*)d_in[1];
    float* out   = (float*)d_out;
    float* order = out + (size_t)B * C * NPIX;   // second output, flat after first

    dim3 grid(HO / RPT, B * C);                  // (7, 2048)
    rrsvm_kernel<<<grid, dim3(BLK), 0, stream>>>(x, s, out, order);
}